// Round 9
// baseline (2718.317 us; speedup 1.0000x reference)
//
#include <hip/hip_runtime.h>

// LSTM encoder-decoder, MI355X. B=1024, S=256, IN=8, H=512, F=96.
// Persistent kernel, 256 wgs (1/CU). R9 = no-LDS-staging architecture built from
// PROVEN primitives only (R7/R8 post-mortem: buffer_inv doesn't exist on gfx950;
// multi-load asm without early-clobber can fault under vmem backpressure):
//  - h exchanged in MFMA-fragment layout hbuf[parity][group][octet][row][8];
//    A-fragments loaded L2->registers with single-load ld16 asm ("=&v").
//  - K-loop in batches of 2 k-steps: 8 loads, then ONE s_waitcnt vmcnt(0) with
//    the 8 fragment registers tied "+v" (orders MFMAs after the drain).
//  - barrier/self-org/store/pointwise/pred: R6 verbatim (green at 2628 us).
// Weights in VGPRs (bw[2][17]=136), c-state in regs, decoder feedback folded.
// Mode B fallback (placement not 32 wgs/XCD): all-MALL sc0 sc1 protocol (R4).

#define Hh 512
#define K2 544
#define BATCH 1024
#define SEQ 256
#define FCAST 96
#define SHS 40                   // sH stride (f16): 80 B rows, 16B-aligned
#define HBP (16 * 64 * 64 * 8)   // hbuf f16 per parity

typedef _Float16 f16;
typedef _Float16 f16x8 __attribute__((ext_vector_type(8)));
typedef float f32x4 __attribute__((ext_vector_type(4)));

__device__ __forceinline__ float sigf(float v) { return 1.0f / (1.0f + __expf(-v)); }
__device__ __forceinline__ float tanhf_(float v) { return 1.0f - 2.0f / (__expf(2.0f * v) + 1.0f); }

__device__ __forceinline__ f16x8 ld16(const f16* p, bool byp) {
  f16x8 d;
  if (byp) asm volatile("global_load_dwordx4 %0, %1, off sc0 sc1" : "=&v"(d) : "v"(p) : "memory");
  else     asm volatile("global_load_dwordx4 %0, %1, off sc0"     : "=&v"(d) : "v"(p) : "memory");
  return d;
}
__device__ __forceinline__ void st16(f16* p, f16x8 v, bool byp) {
  if (byp) asm volatile("global_store_dwordx4 %0, %1, off sc0 sc1" :: "v"(p), "v"(v) : "memory");
  else     asm volatile("global_store_dwordx4 %0, %1, off"         :: "v"(p), "v"(v) : "memory");
}
__device__ __forceinline__ int atomic_add_l2(int* p, int v) {
  int old;
  asm volatile("global_atomic_add %0, %1, %2, off sc0\n\ts_waitcnt vmcnt(0)"
               : "=v"(old) : "v"(p), "v"(v) : "memory");
  return old;
}
// drain all vmem; ties the 8 fragment regs so their consumers schedule after.
__device__ __forceinline__ void wait_frags(f16x8 (&fr)[2][4]) {
  asm volatile("s_waitcnt vmcnt(0)"
               : "+v"(fr[0][0]), "+v"(fr[0][1]), "+v"(fr[0][2]), "+v"(fr[0][3]),
                 "+v"(fr[1][0]), "+v"(fr[1][1]), "+v"(fr[1][2]), "+v"(fr[1][3]));
}

// ---------------- prep: permute + fp16-convert + fold weights ----------------
// col n: nslot=n>>7, c=n&127, w=c>>5, cc=c&31, ct=cc>>4, l4=cc&15;
// gate=ct*2+(l4>>3), j=l4&7, unit=nslot*32+w*8+j; row r=gate*512+unit.
// K: [0,512)=Whh, [512,520)=Wih(enc), [520,544)=0.
__global__ void prep_weights(const float* __restrict__ encWih, const float* __restrict__ encWhh,
                             const float* __restrict__ decWih, const float* __restrict__ decWhh,
                             const float* __restrict__ encBih, const float* __restrict__ encBhh,
                             const float* __restrict__ decBih, const float* __restrict__ decBhh,
                             const float* __restrict__ outW, const float* __restrict__ outB,
                             f16* __restrict__ encT, f16* __restrict__ decPW, f16* __restrict__ decFW,
                             float* __restrict__ bE, float* __restrict__ bP, float* __restrict__ bF) {
  int id = blockIdx.x * 256 + threadIdx.x;
  if (id >= 2048 * 68) return;
  int n = id / 68, c8 = id % 68;
  int nslot = n >> 7, c = n & 127, w = c >> 5, cc = c & 31, ct = cc >> 4, l4v = cc & 15;
  int g = ct * 2 + (l4v >> 3), j = l4v & 7;
  int unit = nslot * 32 + w * 8 + j, r = g * Hh + unit;
  size_t o = (size_t)n * K2 + c8 * 8;
  if (c8 < 64) {
    float dwih = decWih[r];
#pragma unroll
    for (int e = 0; e < 8; ++e) {
      int k = c8 * 8 + e;
      encT[o + e] = (f16)encWhh[(size_t)r * Hh + k];
      float dw = decWhh[(size_t)r * Hh + k];
      decPW[o + e] = (f16)dw;
      decFW[o + e] = (f16)(dw + outW[k] * dwih);
    }
  } else if (c8 == 64) {
#pragma unroll
    for (int e = 0; e < 8; ++e) {
      encT[o + e] = (f16)encWih[r * 8 + e];
      decPW[o + e] = (f16)0.f;
      decFW[o + e] = (f16)0.f;
    }
  } else {
#pragma unroll
    for (int e = 0; e < 8; ++e) {
      encT[o + e] = (f16)0.f;
      decPW[o + e] = (f16)0.f;
      decFW[o + e] = (f16)0.f;
    }
  }
  if (c8 == 0) {
    bE[n] = encBih[r] + encBhh[r];
    float bd = decBih[r] + decBhh[r];
    bP[n] = bd;
    bF[n] = bd + outB[0] * decWih[r];
  }
}

__global__ void init_state(f16* __restrict__ hbuf, float* __restrict__ out,
                           const float* __restrict__ outB, int* __restrict__ sync) {
  int i = blockIdx.x * 256 + threadIdx.x;  // 2048 blocks -> 524288 threads
  unsigned int* hb = (unsigned int*)hbuf;  // 2*HBP f16 = 524288 u32
  if (i < 524288) hb[i] = 0u;
  if (i < BATCH * FCAST) out[i] = outB[0];
  if (i < 2048) sync[i] = 0;
}

// ---------------- persistent kernel ----------------
__global__ __launch_bounds__(256, 1) void lstm_persist(
    const f16* __restrict__ encT, const f16* __restrict__ decPW, const f16* __restrict__ decFW,
    const float* __restrict__ bE, const float* __restrict__ bP, const float* __restrict__ bF,
    const float* __restrict__ x, const float* __restrict__ outW,
    f16* __restrict__ hbuf, float* __restrict__ out, int* __restrict__ sync) {
  __shared__ __align__(16) f16 sH[64 * SHS];  // 5120 B
  __shared__ int sInfo[2];

  int* cnt = sync;            // 16 groups, stride 32 ints
  int* slots = sync + 1024;
  int* arrive = sync + 1032;

  const int T = threadIdx.x;
  const int w = T >> 6, lane = T & 63, l4 = lane & 15, q = lane >> 4;
  const int j = l4 & 7;
  const bool lo = (l4 < 8);

  int xcd;
  asm("s_getreg_b32 %0, hwreg(HW_REG_XCC_ID)" : "=s"(xcd));
  xcd &= 7;

  // ---- one-time self-organization (agent scope) ----
  if (T == 0) {
    int r = __hip_atomic_fetch_add(&slots[xcd], 1, __ATOMIC_RELAXED, __HIP_MEMORY_SCOPE_AGENT);
    sInfo[0] = r;
    __hip_atomic_fetch_add(arrive, 1, __ATOMIC_RELAXED, __HIP_MEMORY_SCOPE_AGENT);
    while (__hip_atomic_load(arrive, __ATOMIC_RELAXED, __HIP_MEMORY_SCOPE_AGENT) < 256)
      __builtin_amdgcn_s_sleep(2);
    int ok = 1;
    for (int xx = 0; xx < 8; ++xx)
      ok &= (__hip_atomic_load(&slots[xx], __ATOMIC_RELAXED, __HIP_MEMORY_SCOPE_AGENT) == 32);
    sInfo[1] = ok;
  }
  __syncthreads();
  const int rank = sInfo[0];
  const bool uni = (sInfo[1] != 0);
  int group, nslot;
  if (uni) { group = xcd * 2 + (rank >> 4); nslot = rank & 15; }
  else     { group = (int)blockIdx.x >> 4;  nslot = (int)blockIdx.x & 15; }
  const int m0 = group * 64, n0 = nslot * 128, u0 = nslot * 32;
  int* myCnt = cnt + group * 32;

  f16x8 bw[2][17];   // 136 VGPRs
  float bias_r[4];
  float cst[2][4];
#pragma unroll
  for (int a = 0; a < 2; ++a)
#pragma unroll
    for (int r = 0; r < 4; ++r) cst[a][r] = 0.f;

  auto loadB = [&](const f16* WT, const float* bias) {
#pragma unroll
    for (int ct = 0; ct < 2; ++ct) {
      const f16* base = &WT[(size_t)(n0 + w * 32 + ct * 16 + l4) * K2 + q * 8];
#pragma unroll
      for (int ks = 0; ks < 17; ++ks) bw[ct][ks] = *(const f16x8*)(base + ks * 32);
    }
#pragma unroll
    for (int g = 0; g < 4; ++g)
      bias_r[g] = bias[n0 + w * 32 + (g >> 1) * 16 + (g & 1) * 8 + j];
  };

  loadB(encT, bE);
  float ow_r = 0.f;
  const int myUnit = u0 + w * 8 + j;
  const int fragBase = q * 512 + l4 * 8;  // lane offset within [octet][row][8]

  for (int s = 0; s < SEQ + FCAST; ++s) {
    const bool enc = s < SEQ;
    if (s == SEQ) {
      loadB(decPW, bP);
      ow_r = outW[myUnit];
    } else if (s == SEQ + 1) {
      loadB(decFW, bF);
    }

    if (s > 0) {
      asm volatile("s_waitcnt vmcnt(0)" ::: "memory");  // drain my h stores
      __syncthreads();
      if (T == 0) {
        if (uni) {
          atomic_add_l2(myCnt, 1);
          while (atomic_add_l2(myCnt, 0) < 16 * s) __builtin_amdgcn_s_sleep(1);
        } else {
          __hip_atomic_fetch_add(myCnt, 1, __ATOMIC_RELAXED, __HIP_MEMORY_SCOPE_AGENT);
          while (__hip_atomic_load(myCnt, __ATOMIC_RELAXED, __HIP_MEMORY_SCOPE_AGENT) < 16 * s)
            __builtin_amdgcn_s_sleep(2);
        }
      }
      __syncthreads();
    }

    const int pin = s & 1, pout = pin ^ 1;
    const f16* hbL = hbuf + (size_t)pin * HBP + (size_t)group * 32768 + fragBase;
    f16* hbO = hbuf + (size_t)pout * HBP + (size_t)group * 32768;

    // ---- GEMM: A-fragments straight from L2 (mode A) / MALL (mode B) ----
    f32x4 acc[4][2];
#pragma unroll
    for (int a = 0; a < 4; ++a)
#pragma unroll
      for (int c = 0; c < 2; ++c) acc[a][c] = (f32x4){0.f, 0.f, 0.f, 0.f};

#pragma unroll
    for (int b = 0; b < 8; ++b) {
      f16x8 fr[2][4];
#pragma unroll
      for (int k2 = 0; k2 < 2; ++k2)
#pragma unroll
        for (int at = 0; at < 4; ++at)
          fr[k2][at] = ld16(&hbL[(b * 2 + k2) * 2048 + at * 128], !uni);
      wait_frags(fr);
#pragma unroll
      for (int k2 = 0; k2 < 2; ++k2) {
        const int ks = b * 2 + k2;
#pragma unroll
        for (int at = 0; at < 4; ++at) {
          acc[at][0] =
              __builtin_amdgcn_mfma_f32_16x16x32_f16(fr[k2][at], bw[0][ks], acc[at][0], 0, 0, 0);
          acc[at][1] =
              __builtin_amdgcn_mfma_f32_16x16x32_f16(fr[k2][at], bw[1][ks], acc[at][1], 0, 0, 0);
        }
      }
    }

    if (enc) {  // ks=16: x chunk — q==0 lanes carry x (k 512..519); rest zero-weighted
#pragma unroll
      for (int at = 0; at < 4; ++at) {
        f16x8 af = {(f16)0.f, (f16)0.f, (f16)0.f, (f16)0.f,
                    (f16)0.f, (f16)0.f, (f16)0.f, (f16)0.f};
        if (q == 0) {
          const float* xp = &x[((size_t)(m0 + at * 16 + l4) * SEQ + s) * 8];
          float4 xa = *(const float4*)xp, xb = *(const float4*)(xp + 4);
          af = f16x8{(f16)xa.x, (f16)xa.y, (f16)xa.z, (f16)xa.w,
                     (f16)xb.x, (f16)xb.y, (f16)xb.z, (f16)xb.w};
        }
        acc[at][0] = __builtin_amdgcn_mfma_f32_16x16x32_f16(af, bw[0][16], acc[at][0], 0, 0, 0);
        acc[at][1] = __builtin_amdgcn_mfma_f32_16x16x32_f16(af, bw[1][16], acc[at][1], 0, 0, 0);
      }
    }

    // ---- pointwise: lane pair l4 <-> l4+8 exchanges (i,g)<->(f,o) ----
#pragma unroll
    for (int ah = 0; ah < 2; ++ah) {
#pragma unroll
      for (int r = 0; r < 4; ++r) {
        int atL = ah, atH = ah + 2;
        float xiL = acc[atL][0][r], xgL = acc[atL][1][r];
        float xiH = acc[atH][0][r], xgH = acc[atH][1][r];
        float payload0 = lo ? xiH : xiL;
        float payload1 = lo ? xgH : xgL;
        float recv0 = __shfl_xor(payload0, 8, 16);
        float recv1 = __shfl_xor(payload1, 8, 16);
        float pi = (lo ? xiL : recv0) + bias_r[0];
        float pf = (lo ? recv0 : xiH) + bias_r[1];
        float pg = (lo ? xgL : recv1) + bias_r[2];
        float po = (lo ? recv1 : xgH) + bias_r[3];
        float ig = sigf(pi), fg = sigf(pf), gg = tanhf_(pg), og = sigf(po);
        float cn = fg * cst[ah][r] + ig * gg;
        cst[ah][r] = cn;
        float hn = og * tanhf_(cn);
        int at = lo ? atL : atH;
        int row = at * 16 + q * 4 + r;
        sH[row * SHS + w * 8 + j] = (f16)hn;
        if (!enc) {
          float pp = hn * ow_r;
          pp += __shfl_xor(pp, 1, 16);
          pp += __shfl_xor(pp, 2, 16);
          pp += __shfl_xor(pp, 4, 16);
          if (j == 0) atomicAdd(&out[(m0 + row) * FCAST + (s - SEQ)], pp);
        }
      }
    }
    __syncthreads();

    // ---- store h in fragment layout: octet nslot*4+seg, rows 0..63 ----
    {
      int row = lane, seg = w;
      f16x8 hv = *(const f16x8*)&sH[row * SHS + seg * 8];
      st16(&hbO[((nslot * 4 + seg) * 64 + row) * 8], hv, !uni);
    }
  }
}

extern "C" void kernel_launch(void* const* d_in, const int* in_sizes, int n_in, void* d_out,
                              int out_size, void* d_ws, size_t ws_size, hipStream_t stream) {
  const float* x = (const float*)d_in[0];
  const float* encWih = (const float*)d_in[1];
  const float* encWhh = (const float*)d_in[2];
  const float* encBih = (const float*)d_in[3];
  const float* encBhh = (const float*)d_in[4];
  const float* decWih = (const float*)d_in[5];
  const float* decWhh = (const float*)d_in[6];
  const float* decBih = (const float*)d_in[7];
  const float* decBhh = (const float*)d_in[8];
  const float* outW = (const float*)d_in[9];
  const float* outB = (const float*)d_in[10];
  float* out = (float*)d_out;

  char* ws = (char*)d_ws;
  f16* encT = (f16*)ws;                       // 3 x 2048*544*2 B = 6.7 MB
  f16* decPW = encT + 2048 * K2;
  f16* decFW = decPW + 2048 * K2;
  f16* hbuf = decFW + 2048 * K2;              // 2 MB
  float* bE = (float*)(hbuf + 2 * HBP);
  float* bP = bE + 2048;
  float* bF = bP + 2048;
  int* sync = (int*)(bF + 2048);              // 8 KB

  prep_weights<<<544, 256, 0, stream>>>(encWih, encWhh, decWih, decWhh, encBih, encBhh, decBih,
                                        decBhh, outW, outB, encT, decPW, decFW, bE, bP, bF);
  init_state<<<2048, 256, 0, stream>>>(hbuf, out, outB, sync);
  lstm_persist<<<256, 256, 0, stream>>>(encT, decPW, decFW, bE, bP, bF, x, outW, hbuf, out, sync);
}